// Round 5
// baseline (8561.385 us; speedup 1.0000x reference)
//
#include <hip/hip_runtime.h>
#include <stdint.h>

#define TLEN 512
#define HDIM 512
#define DDIM 128
#define NCLS 10
#define P 8                               // batch-tiles per WG

typedef float f32x4 __attribute__((ext_vector_type(4)));
typedef short bf16x8 __attribute__((ext_vector_type(8)));
typedef unsigned long long u64;

__device__ __forceinline__ unsigned short f2bf(float f) {
  union { float f; unsigned u; } v; v.f = f;
  return (unsigned short)((v.u + 0x7FFFu + ((v.u >> 16) & 1u)) >> 16);
}
__device__ __forceinline__ float bf2f(unsigned short h) {
  union { unsigned u; float f; } v; v.u = ((unsigned)h) << 16; return v.f;
}
__device__ __forceinline__ float sigm(float x) {
  return __builtin_amdgcn_rcpf(1.0f + __expf(-x));
}
__device__ __forceinline__ u64 ald(const u64* p) {
  return __hip_atomic_load(p, __ATOMIC_RELAXED, __HIP_MEMORY_SCOPE_AGENT);
}
__device__ __forceinline__ void ast16(unsigned short* p, unsigned short v) {
  __hip_atomic_store(p, v, __ATOMIC_RELAXED, __HIP_MEMORY_SCOPE_AGENT);
}
__device__ __forceinline__ void astd(unsigned* p, unsigned v) {
  __hip_atomic_store(p, v, __ATOMIC_RELAXED, __HIP_MEMORY_SCOPE_AGENT);
}

// ---------------- gate tables: G[g][v][h], g in {f,i,c(pre-sigmoided),o} ----
__global__ void k_gates(const float* __restrict__ emb,
                        const float* __restrict__ Wfx, const float* __restrict__ bf_,
                        const float* __restrict__ Wix, const float* __restrict__ bi_,
                        const float* __restrict__ Wcx, const float* __restrict__ bc_,
                        const float* __restrict__ Wox, const float* __restrict__ bo_,
                        float* __restrict__ G) {
  int tid = blockIdx.x * 256 + threadIdx.x;          // 0..6143
  int h = tid & (HDIM - 1);
  int v = (tid >> 9) % 3;
  int g = tid / (3 * HDIM);
  const float* W; const float* bb;
  if (g == 0)      { W = Wfx; bb = bf_; }
  else if (g == 1) { W = Wix; bb = bi_; }
  else if (g == 2) { W = Wcx; bb = bc_; }
  else             { W = Wox; bb = bo_; }
  const float* e = emb + v * DDIM;
  const float* w = W + h * DDIM;
  float s = bb[h];
  #pragma unroll 8
  for (int d = 0; d < DDIM; ++d) s += e[d] * w[d];
  if (g == 2) s = sigm(s);                           // pre-sigmoid the c-gate
  G[tid] = s;
}

// ---------------- weight pack: register-resident B-fragments ----------------
// pk2: [hs(8)][nt(4)][gate(2)][kt(16)][lane(64)][e(8)] bf16
__global__ void k_pack_fi(const float* __restrict__ Wfh, const float* __restrict__ Wih,
                          unsigned short* __restrict__ pk) {
  int tid = blockIdx.x * 256 + threadIdx.x;          // 0..65535
  int l  = tid & 63;
  int kt = (tid >> 6) & 15;
  int g  = (tid >> 10) & 1;
  int nt = (tid >> 11) & 3;
  int hs = (tid >> 13) & 7;
  int n  = hs * 64 + nt * 16 + (l & 15);
  int k0 = kt * 32 + (l >> 4) * 8;
  const float* src = (g ? Wih : Wfh) + n * HDIM + k0;
  unsigned short* dst = pk + (size_t)tid * 8;
  #pragma unroll
  for (int e = 0; e < 8; ++e) dst[e] = f2bf(src[e]);
}

// pko: [hs(8)][nt(4)][kt(16)][lane(64)][e(8)] bf16
__global__ void k_pack_o(const float* __restrict__ Woh, unsigned short* __restrict__ pk) {
  int tid = blockIdx.x * 256 + threadIdx.x;          // 0..32767
  int l  = tid & 63;
  int kt = (tid >> 6) & 15;
  int nt = (tid >> 10) & 3;
  int hs = (tid >> 12) & 7;
  int n  = hs * 64 + nt * 16 + (l & 15);
  int k0 = kt * 32 + (l >> 4) * 8;
  const float* src = Woh + n * HDIM + k0;
  unsigned short* dst = pk + (size_t)tid * 8;
  #pragma unroll
  for (int e = 0; e < 8; ++e) dst[e] = f2bf(src[e]);
}

// ---------------- scan: 16 WGs = 2 slots x 8 h-slices; P=8 tiles per WG -----
// Per WG: 8 tiles x (M=16, N=64, K=512). Weights in regs for all 512 steps.
// One drain + one flag signal per 8 tile-steps — sync latency amortized 8x.
__global__ __launch_bounds__(256, 1)
void k_scan(const int* __restrict__ x, const float* __restrict__ G,
            const unsigned short* __restrict__ pk2,
            const unsigned short* __restrict__ pko,
            char* __restrict__ cbuf, unsigned* __restrict__ flg,
            unsigned short* __restrict__ hfin) {
  extern __shared__ char smem[];
  uint4 (*lds_a)[16][64]      = (uint4 (*)[16][64])smem;             // 128 KB
  float (*gts)[68]            = (float (*)[68])(smem + 131072);      // 3264 B
  unsigned char (*xv)[16][64] = (unsigned char (*)[16][64])(smem + 134336); // 8 KB

  const int tid  = threadIdx.x;
  const int lane = tid & 63;
  const int w    = tid >> 6;                         // wave = nt (0..3)
  const int s    = blockIdx.x >> 3;                  // slot 0..1 (bt = s*8+j)
  const int hs   = blockIdx.x & 7;                   // peers spread across XCDs

  for (int jj = tid; jj < 12 * 64; jj += 256) {
    int gv = jj >> 6, c = jj & 63;
    gts[gv][c] = G[gv * HDIM + hs * 64 + c];
  }
  for (int jj = tid; jj < P * 16 * 64; jj += 256)    // c_0 = 0
    ((uint4*)lds_a)[jj] = uint4{0, 0, 0, 0};

  bf16x8 wf[16], wi[16];
  {
    const bf16x8* ws = (const bf16x8*)pk2 + (size_t)((hs * 4 + w) * 2) * (16 * 64) + lane;
    #pragma unroll
    for (int kt = 0; kt < 16; ++kt) { wf[kt] = ws[kt * 64]; wi[kt] = ws[(16 + kt) * 64]; }
  }

  float cf[P][4];
  #pragma unroll
  for (int j = 0; j < P; ++j)
    #pragma unroll
    for (int r = 0; r < 4; ++r) cf[j][r] = 0.f;

  const int rgrp = (lane >> 4) * 4;                  // C/D row base (batch row)
  const int coll = lane & 15;                        // C/D col (within 16-tile)
  const int col  = w * 16 + coll;                    // h col within slice
  const int colb = (hs * 64 + col) * 2;              // byte offset within a row
  const int rowb = (lane & 15) * 1024 + (lane >> 4) * 16;
  const f32x4 zz = {0.f, 0.f, 0.f, 0.f};

  __syncthreads();

  for (int t = 0; t < TLEN; ++t) {
    if ((t & 63) == 0) {                             // token refill (64-step chunk)
      #pragma unroll 4
      for (int k = 0; k < 32; ++k) {
        int e  = tid + k * 256;
        int tt = e & 63, row = (e >> 6) & 15, j = e >> 10;
        xv[j][row][tt] = (unsigned char)x[((s * P + j) * 16 + row) * TLEN + t + tt];
      }
    }
    if (t > 0) {
      const unsigned tgr = (unsigned)t;
      const int par_r = t & 1;
      const u64* fp = (const u64*)(flg + (par_r * 2 + s) * 16);
      const u64 pat2 = ((u64)tgr << 32) | (u64)tgr;
      u64 g0, g1, g2, g3;
      do {
        g0 = ald(fp + 0); g1 = ald(fp + 1); g2 = ald(fp + 2); g3 = ald(fp + 3);
      } while (((g0 ^ pat2) | (g1 ^ pat2) | (g2 ^ pat2) | (g3 ^ pat2)) != 0ULL);
      asm volatile("" ::: "memory");                 // no data load before flag pass

      #pragma unroll
      for (int j = 0; j < P; ++j) {
        const char* rb = cbuf + par_r * 262144 + (s * P + j) * 16384 + rowb;
        #pragma unroll
        for (int i = 0; i < 4; ++i) {
          const int kt = (w << 2) | i;
          const u64* p = (const u64*)(rb + kt * 64);
          u64 lo = ald(p + 0), hi = ald(p + 1);
          uint4 q;
          q.x = (unsigned)lo; q.y = (unsigned)(lo >> 32);
          q.z = (unsigned)hi; q.w = (unsigned)(hi >> 32);
          lds_a[j][kt][lane] = q;
        }
      }
    }
    __syncthreads();                                 // lds_a (+ xv refill) ready

    if (t < TLEN - 1) {
      const unsigned tg = (unsigned)(t + 1);
      const int par_w = (t + 1) & 1;
      char* dbase = cbuf + par_w * 262144 + s * P * 16384;
      #pragma unroll
      for (int j = 0; j < P; ++j) {
        f32x4 af0 = zz, af1 = zz, ai0 = zz, ai1 = zz;
        #pragma unroll
        for (int kt = 0; kt < 16; kt += 2) {
          union { uint4 q; bf16x8 v; } u0, u1;
          u0.q = lds_a[j][kt][lane];
          u1.q = lds_a[j][kt + 1][lane];
          af0 = __builtin_amdgcn_mfma_f32_16x16x32_bf16(u0.v, wf[kt], af0, 0, 0, 0);
          ai0 = __builtin_amdgcn_mfma_f32_16x16x32_bf16(u0.v, wi[kt], ai0, 0, 0, 0);
          af1 = __builtin_amdgcn_mfma_f32_16x16x32_bf16(u1.v, wf[kt + 1], af1, 0, 0, 0);
          ai1 = __builtin_amdgcn_mfma_f32_16x16x32_bf16(u1.v, wi[kt + 1], ai1, 0, 0, 0);
        }
        #pragma unroll
        for (int r = 0; r < 4; ++r) {
          int vv = xv[j][rgrp + r][t & 63];
          float fg = sigm(af0[r] + af1[r] + gts[0 + vv][col]);
          float ig = sigm(ai0[r] + ai1[r] + gts[3 + vv][col]);
          float sc = gts[6 + vv][col];               // pre-sigmoided c-gate
          float cn = sc * ig + cf[j][r] * fg;
          cf[j][r] = cn;
          ast16((unsigned short*)(dbase + j * 16384 + (rgrp + r) * 1024 + colb), f2bf(cn));
        }
      }
      __syncthreads();                               // all stores drained (vmcnt 0)
      if (tid == 0) astd(flg + (par_w * 2 + s) * 16 + hs, tg);
    } else {
      // ---- final step t = 511: f, i and o gates; h = tanh(c)*o -------------
      bf16x8 wo[16];
      const bf16x8* os = (const bf16x8*)pko + (size_t)(hs * 4 + w) * (16 * 64) + lane;
      #pragma unroll
      for (int kt = 0; kt < 16; ++kt) wo[kt] = os[kt * 64];
      #pragma unroll
      for (int j = 0; j < P; ++j) {
        f32x4 af0 = zz, af1 = zz, ai0 = zz, ai1 = zz, ao0 = zz, ao1 = zz;
        #pragma unroll
        for (int kt = 0; kt < 16; kt += 2) {
          union { uint4 q; bf16x8 v; } u0, u1;
          u0.q = lds_a[j][kt][lane];
          u1.q = lds_a[j][kt + 1][lane];
          af0 = __builtin_amdgcn_mfma_f32_16x16x32_bf16(u0.v, wf[kt], af0, 0, 0, 0);
          ai0 = __builtin_amdgcn_mfma_f32_16x16x32_bf16(u0.v, wi[kt], ai0, 0, 0, 0);
          ao0 = __builtin_amdgcn_mfma_f32_16x16x32_bf16(u0.v, wo[kt], ao0, 0, 0, 0);
          af1 = __builtin_amdgcn_mfma_f32_16x16x32_bf16(u1.v, wf[kt + 1], af1, 0, 0, 0);
          ai1 = __builtin_amdgcn_mfma_f32_16x16x32_bf16(u1.v, wi[kt + 1], ai1, 0, 0, 0);
          ao1 = __builtin_amdgcn_mfma_f32_16x16x32_bf16(u1.v, wo[kt + 1], ao1, 0, 0, 0);
        }
        #pragma unroll
        for (int r = 0; r < 4; ++r) {
          int vv = xv[j][rgrp + r][63];
          float fg = sigm(af0[r] + af1[r] + gts[0 + vv][col]);
          float ig = sigm(ai0[r] + ai1[r] + gts[3 + vv][col]);
          float sc = gts[6 + vv][col];
          float cn = sc * ig + cf[j][r] * fg;
          float og = sigm(ao0[r] + ao1[r] + gts[9 + vv][col]);
          float hv = tanhf(cn) * og;
          hfin[((s * P + j) * 16 + rgrp + r) * HDIM + hs * 64 + col] = f2bf(hv);
        }
      }
    }
  }
}

// ---------------- classifier head + log_softmax: one wave per row -----------
__global__ __launch_bounds__(64)
void k_head(const unsigned short* __restrict__ hfin, const float* __restrict__ Wph,
            const float* __restrict__ bp, float* __restrict__ out) {
  const int b = blockIdx.x;
  const int lane = threadIdx.x;
  float acc[NCLS];
  #pragma unroll
  for (int c = 0; c < NCLS; ++c) acc[c] = 0.f;
  const unsigned short* hrow = hfin + (size_t)b * HDIM;
  for (int k = lane; k < HDIM; k += 64) {
    float hv = bf2f(hrow[k]);
    #pragma unroll
    for (int c = 0; c < NCLS; ++c) acc[c] += hv * Wph[c * HDIM + k];
  }
  #pragma unroll
  for (int c = 0; c < NCLS; ++c)
    #pragma unroll
    for (int off = 32; off > 0; off >>= 1)
      acc[c] += __shfl_down(acc[c], off, 64);
  if (lane == 0) {
    float p[NCLS]; float m = -1e30f;
    #pragma unroll
    for (int c = 0; c < NCLS; ++c) { p[c] = acc[c] + bp[c]; m = fmaxf(m, p[c]); }
    float s = 0.f;
    #pragma unroll
    for (int c = 0; c < NCLS; ++c) s += __expf(p[c] - m);
    const float ls = __logf(s);
    #pragma unroll
    for (int c = 0; c < NCLS; ++c) out[b * NCLS + c] = p[c] - m - ls;
  }
}

extern "C" void kernel_launch(void* const* d_in, const int* in_sizes, int n_in,
                              void* d_out, int out_size, void* d_ws, size_t ws_size,
                              hipStream_t stream) {
  const int*   x   = (const int*)d_in[0];
  const float* emb = (const float*)d_in[1];
  const float* Wfx = (const float*)d_in[2];
  const float* Wfh = (const float*)d_in[3];
  const float* bf_ = (const float*)d_in[4];
  const float* Wix = (const float*)d_in[5];
  const float* Wih = (const float*)d_in[6];
  const float* bi_ = (const float*)d_in[7];
  const float* Wox = (const float*)d_in[8];
  const float* Woh = (const float*)d_in[9];
  const float* bo_ = (const float*)d_in[10];
  const float* Wcx = (const float*)d_in[11];
  const float* bc_ = (const float*)d_in[12];
  const float* Wph = (const float*)d_in[13];
  const float* bp_ = (const float*)d_in[14];

  char* ws = (char*)d_ws;
  float*          G    = (float*)(ws);                      // 24 KB   @ 0
  unsigned short* hfin = (unsigned short*)(ws + 32768);     // 256 KB  @ 32K
  char*           cbuf = (char*)(ws + 524288);              // 512 KB  @ 512K (2 par x 16 bt x 16KB)
  unsigned*       flg  = (unsigned*)(ws + 1048576);         // 2 KB    @ 1M
  unsigned short* pk2  = (unsigned short*)(ws + 1114112);   // 1 MB    @ 1M+64K
  unsigned short* pko  = (unsigned short*)(ws + 2162688);   // 512 KB  @ 2M+64K

  hipMemsetAsync(flg, 0, 2048, stream);                     // fresh flags every call
  hipLaunchKernelGGL(k_gates,   dim3(24),  dim3(256), 0, stream,
                     emb, Wfx, bf_, Wix, bi_, Wcx, bc_, Wox, bo_, G);
  hipLaunchKernelGGL(k_pack_fi, dim3(256), dim3(256), 0, stream, Wfh, Wih, pk2);
  hipLaunchKernelGGL(k_pack_o,  dim3(128), dim3(256), 0, stream, Woh, pko);
  hipLaunchKernelGGL(k_scan,    dim3(16),  dim3(256), 142592, stream,
                     x, G, pk2, pko, cbuf, flg, hfin);
  hipLaunchKernelGGL(k_head,    dim3(256), dim3(64),  0, stream, hfin, Wph, bp_, (float*)d_out);
}

// Round 6
// 5523.149 us; speedup vs baseline: 1.5501x; 1.5501x over previous
//
#include <hip/hip_runtime.h>
#include <stdint.h>

#define TLEN 512
#define HDIM 512
#define DDIM 128
#define NCLS 10
#define P 4                               // batch-tiles per WG

typedef float f32x4 __attribute__((ext_vector_type(4)));
typedef short bf16x8 __attribute__((ext_vector_type(8)));
typedef unsigned long long u64;

__device__ __forceinline__ unsigned short f2bf(float f) {
  union { float f; unsigned u; } v; v.f = f;
  return (unsigned short)((v.u + 0x7FFFu + ((v.u >> 16) & 1u)) >> 16);
}
__device__ __forceinline__ float bf2f(unsigned short h) {
  union { unsigned u; float f; } v; v.u = ((unsigned)h) << 16; return v.f;
}
__device__ __forceinline__ float sigm(float x) {
  return __builtin_amdgcn_rcpf(1.0f + __expf(-x));
}
__device__ __forceinline__ u64 ald(const u64* p) {
  return __hip_atomic_load(p, __ATOMIC_RELAXED, __HIP_MEMORY_SCOPE_AGENT);
}
__device__ __forceinline__ void ast16(unsigned short* p, unsigned short v) {
  __hip_atomic_store(p, v, __ATOMIC_RELAXED, __HIP_MEMORY_SCOPE_AGENT);
}
__device__ __forceinline__ void astd(unsigned* p, unsigned v) {
  __hip_atomic_store(p, v, __ATOMIC_RELAXED, __HIP_MEMORY_SCOPE_AGENT);
}

// batched cache-bypassing 16B load: issued without compiler tracking (no
// per-load waits); caller does ONE s_waitcnt vmcnt(0) after issuing all.
#define GLOAD(dst, addr) \
  asm volatile("global_load_dwordx4 %0, %1, off sc0 sc1" : "=&v"(dst) : "v"(addr))

// ---------------- gate tables: G[g][v][h], g in {f,i,c(pre-sigmoided),o} ----
__global__ void k_gates(const float* __restrict__ emb,
                        const float* __restrict__ Wfx, const float* __restrict__ bf_,
                        const float* __restrict__ Wix, const float* __restrict__ bi_,
                        const float* __restrict__ Wcx, const float* __restrict__ bc_,
                        const float* __restrict__ Wox, const float* __restrict__ bo_,
                        float* __restrict__ G) {
  int tid = blockIdx.x * 256 + threadIdx.x;          // 0..6143
  int h = tid & (HDIM - 1);
  int v = (tid >> 9) % 3;
  int g = tid / (3 * HDIM);
  const float* W; const float* bb;
  if (g == 0)      { W = Wfx; bb = bf_; }
  else if (g == 1) { W = Wix; bb = bi_; }
  else if (g == 2) { W = Wcx; bb = bc_; }
  else             { W = Wox; bb = bo_; }
  const float* e = emb + v * DDIM;
  const float* w = W + h * DDIM;
  float s = bb[h];
  #pragma unroll 8
  for (int d = 0; d < DDIM; ++d) s += e[d] * w[d];
  if (g == 2) s = sigm(s);                           // pre-sigmoid the c-gate
  G[tid] = s;
}

// ---------------- weight pack: register-resident B-fragments ----------------
// pk2: [hs(8)][nt(4)][gate(2)][kt(16)][lane(64)][e(8)] bf16
__global__ void k_pack_fi(const float* __restrict__ Wfh, const float* __restrict__ Wih,
                          unsigned short* __restrict__ pk) {
  int tid = blockIdx.x * 256 + threadIdx.x;          // 0..65535
  int l  = tid & 63;
  int kt = (tid >> 6) & 15;
  int g  = (tid >> 10) & 1;
  int nt = (tid >> 11) & 3;
  int hs = (tid >> 13) & 7;
  int n  = hs * 64 + nt * 16 + (l & 15);
  int k0 = kt * 32 + (l >> 4) * 8;
  const float* src = (g ? Wih : Wfh) + n * HDIM + k0;
  unsigned short* dst = pk + (size_t)tid * 8;
  #pragma unroll
  for (int e = 0; e < 8; ++e) dst[e] = f2bf(src[e]);
}

// pko: [hs(8)][nt(4)][kt(16)][lane(64)][e(8)] bf16
__global__ void k_pack_o(const float* __restrict__ Woh, unsigned short* __restrict__ pk) {
  int tid = blockIdx.x * 256 + threadIdx.x;          // 0..32767
  int l  = tid & 63;
  int kt = (tid >> 6) & 15;
  int nt = (tid >> 10) & 3;
  int hs = (tid >> 12) & 7;
  int n  = hs * 64 + nt * 16 + (l & 15);
  int k0 = kt * 32 + (l >> 4) * 8;
  const float* src = Woh + n * HDIM + k0;
  unsigned short* dst = pk + (size_t)tid * 8;
  #pragma unroll
  for (int e = 0; e < 8; ++e) dst[e] = f2bf(src[e]);
}

// ---------------- scan: 32 WGs = 4 slots x 8 h-slices; P=4 tiles per WG -----
// Per WG: 4 tiles x (M=16, N=64, K=512). Weights in regs for all 512 steps.
// One drain + one flag + one poll per 4 tile-steps; data loads batched in asm.
__global__ __launch_bounds__(256, 1)
void k_scan(const int* __restrict__ x, const float* __restrict__ G,
            const unsigned short* __restrict__ pk2,
            const unsigned short* __restrict__ pko,
            char* __restrict__ cbuf, unsigned* __restrict__ flg,
            unsigned short* __restrict__ hfin) {
  extern __shared__ char smem[];
  uint4 (*lds_a)[16][64] = (uint4 (*)[16][64])smem;          // P*16 KB = 64 KB
  float (*gts)[68]       = (float (*)[68])(smem + P * 16384); // 3264 B

  const int tid  = threadIdx.x;
  const int lane = tid & 63;
  const int w    = tid >> 6;                         // wave = nt (0..3)
  const int s    = blockIdx.x & 3;                   // slot: tiles s*4..s*4+3
  const int hs   = blockIdx.x >> 2;                  // h-slice 0..7

  for (int jj = tid; jj < 12 * 64; jj += 256) {
    int gv = jj >> 6, c = jj & 63;
    gts[gv][c] = G[gv * HDIM + hs * 64 + c];
  }
  for (int jj = tid; jj < P * 16 * 64; jj += 256)    // c_0 = 0
    ((uint4*)lds_a)[jj] = uint4{0, 0, 0, 0};

  bf16x8 wf[16], wi[16];
  {
    const bf16x8* ws = (const bf16x8*)pk2 + (size_t)((hs * 4 + w) * 2) * (16 * 64) + lane;
    #pragma unroll
    for (int kt = 0; kt < 16; ++kt) { wf[kt] = ws[kt * 64]; wi[kt] = ws[(16 + kt) * 64]; }
  }

  float cf[P][4];
  #pragma unroll
  for (int j = 0; j < P; ++j)
    #pragma unroll
    for (int r = 0; r < 4; ++r) cf[j][r] = 0.f;

  const int rgrp = (lane >> 4) * 4;                  // C/D row base (batch row)
  const int coll = lane & 15;                        // C/D col (within 16-tile)
  const int col  = w * 16 + coll;                    // h col within slice
  const int colb = (hs * 64 + col) * 2;              // byte offset within a row
  const int rowb = (lane & 15) * 1024 + (lane >> 4) * 16;
  const f32x4 zz = {0.f, 0.f, 0.f, 0.f};

  __syncthreads();

  for (int t = 0; t < TLEN; ++t) {
    if (t > 0) {
      const unsigned tgr = (unsigned)t;
      const int par_r = t & 1;
      const u64* fp = (const u64*)(flg + (par_r * 4 + s) * 16);
      const u64 pat2 = ((u64)tgr << 32) | (u64)tgr;
      u64 g0, g1, g2, g3;
      do {
        g0 = ald(fp + 0); g1 = ald(fp + 1); g2 = ald(fp + 2); g3 = ald(fp + 3);
      } while (((g0 ^ pat2) | (g1 ^ pat2) | (g2 ^ pat2) | (g3 ^ pat2)) != 0ULL);
      asm volatile("" ::: "memory");                 // no data load before flag pass

      // batched cache-bypass loads: issue all 16, ONE wait, then LDS share
      const char* rb = cbuf + par_r * 262144 + s * P * 16384 + rowb + ((w << 2)) * 64;
      uint4 q[P][4];
      #pragma unroll
      for (int j = 0; j < P; ++j)
        #pragma unroll
        for (int i = 0; i < 4; ++i)
          GLOAD(q[j][i], rb + j * 16384 + i * 64);
      asm volatile("s_waitcnt vmcnt(0)" ::: "memory");
      __builtin_amdgcn_sched_barrier(0);
      #pragma unroll
      for (int j = 0; j < P; ++j)
        #pragma unroll
        for (int i = 0; i < 4; ++i)
          lds_a[j][(w << 2) | i][lane] = q[j][i];
    }
    __syncthreads();                                 // lds_a ready

    if (t < TLEN - 1) {
      const unsigned tg = (unsigned)(t + 1);
      const int par_w = (t + 1) & 1;
      char* dbase = cbuf + par_w * 262144 + s * P * 16384;
      #pragma unroll
      for (int j = 0; j < P; ++j) {
        f32x4 af0 = zz, af1 = zz, ai0 = zz, ai1 = zz;
        #pragma unroll
        for (int kt = 0; kt < 16; kt += 2) {
          union { uint4 q; bf16x8 v; } u0, u1;
          u0.q = lds_a[j][kt][lane];
          u1.q = lds_a[j][kt + 1][lane];
          af0 = __builtin_amdgcn_mfma_f32_16x16x32_bf16(u0.v, wf[kt], af0, 0, 0, 0);
          ai0 = __builtin_amdgcn_mfma_f32_16x16x32_bf16(u0.v, wi[kt], ai0, 0, 0, 0);
          af1 = __builtin_amdgcn_mfma_f32_16x16x32_bf16(u1.v, wf[kt + 1], af1, 0, 0, 0);
          ai1 = __builtin_amdgcn_mfma_f32_16x16x32_bf16(u1.v, wi[kt + 1], ai1, 0, 0, 0);
        }
        #pragma unroll
        for (int r = 0; r < 4; ++r) {
          int vv = x[((s * P + j) * 16 + rgrp + r) * TLEN + t];
          float fg = sigm(af0[r] + af1[r] + gts[0 + vv][col]);
          float ig = sigm(ai0[r] + ai1[r] + gts[3 + vv][col]);
          float sc = gts[6 + vv][col];               // pre-sigmoided c-gate
          float cn = sc * ig + cf[j][r] * fg;
          cf[j][r] = cn;
          ast16((unsigned short*)(dbase + j * 16384 + (rgrp + r) * 1024 + colb), f2bf(cn));
        }
      }
      __syncthreads();                               // all stores drained (vmcnt 0)
      if (tid == 0) astd(flg + (par_w * 4 + s) * 16 + hs, tg);
    } else {
      // ---- final step t = 511: f, i and o gates; h = tanh(c)*o -------------
      bf16x8 wo[16];
      const bf16x8* os = (const bf16x8*)pko + (size_t)(hs * 4 + w) * (16 * 64) + lane;
      #pragma unroll
      for (int kt = 0; kt < 16; ++kt) wo[kt] = os[kt * 64];
      #pragma unroll
      for (int j = 0; j < P; ++j) {
        f32x4 af0 = zz, af1 = zz, ai0 = zz, ai1 = zz, ao0 = zz, ao1 = zz;
        #pragma unroll
        for (int kt = 0; kt < 16; kt += 2) {
          union { uint4 q; bf16x8 v; } u0, u1;
          u0.q = lds_a[j][kt][lane];
          u1.q = lds_a[j][kt + 1][lane];
          af0 = __builtin_amdgcn_mfma_f32_16x16x32_bf16(u0.v, wf[kt], af0, 0, 0, 0);
          ai0 = __builtin_amdgcn_mfma_f32_16x16x32_bf16(u0.v, wi[kt], ai0, 0, 0, 0);
          ao0 = __builtin_amdgcn_mfma_f32_16x16x32_bf16(u0.v, wo[kt], ao0, 0, 0, 0);
          af1 = __builtin_amdgcn_mfma_f32_16x16x32_bf16(u1.v, wf[kt + 1], af1, 0, 0, 0);
          ai1 = __builtin_amdgcn_mfma_f32_16x16x32_bf16(u1.v, wi[kt + 1], ai1, 0, 0, 0);
          ao1 = __builtin_amdgcn_mfma_f32_16x16x32_bf16(u1.v, wo[kt + 1], ao1, 0, 0, 0);
        }
        #pragma unroll
        for (int r = 0; r < 4; ++r) {
          int vv = x[((s * P + j) * 16 + rgrp + r) * TLEN + t];
          float fg = sigm(af0[r] + af1[r] + gts[0 + vv][col]);
          float ig = sigm(ai0[r] + ai1[r] + gts[3 + vv][col]);
          float sc = gts[6 + vv][col];
          float cn = sc * ig + cf[j][r] * fg;
          float og = sigm(ao0[r] + ao1[r] + gts[9 + vv][col]);
          float hv = tanhf(cn) * og;
          hfin[((s * P + j) * 16 + rgrp + r) * HDIM + hs * 64 + col] = f2bf(hv);
        }
      }
    }
  }
}

// ---------------- classifier head + log_softmax: one wave per row -----------
__global__ __launch_bounds__(64)
void k_head(const unsigned short* __restrict__ hfin, const float* __restrict__ Wph,
            const float* __restrict__ bp, float* __restrict__ out) {
  const int b = blockIdx.x;
  const int lane = threadIdx.x;
  float acc[NCLS];
  #pragma unroll
  for (int c = 0; c < NCLS; ++c) acc[c] = 0.f;
  const unsigned short* hrow = hfin + (size_t)b * HDIM;
  for (int k = lane; k < HDIM; k += 64) {
    float hv = bf2f(hrow[k]);
    #pragma unroll
    for (int c = 0; c < NCLS; ++c) acc[c] += hv * Wph[c * HDIM + k];
  }
  #pragma unroll
  for (int c = 0; c < NCLS; ++c)
    #pragma unroll
    for (int off = 32; off > 0; off >>= 1)
      acc[c] += __shfl_down(acc[c], off, 64);
  if (lane == 0) {
    float p[NCLS]; float m = -1e30f;
    #pragma unroll
    for (int c = 0; c < NCLS; ++c) { p[c] = acc[c] + bp[c]; m = fmaxf(m, p[c]); }
    float s = 0.f;
    #pragma unroll
    for (int c = 0; c < NCLS; ++c) s += __expf(p[c] - m);
    const float ls = __logf(s);
    #pragma unroll
    for (int c = 0; c < NCLS; ++c) out[b * NCLS + c] = p[c] - m - ls;
  }
}

extern "C" void kernel_launch(void* const* d_in, const int* in_sizes, int n_in,
                              void* d_out, int out_size, void* d_ws, size_t ws_size,
                              hipStream_t stream) {
  const int*   x   = (const int*)d_in[0];
  const float* emb = (const float*)d_in[1];
  const float* Wfx = (const float*)d_in[2];
  const float* Wfh = (const float*)d_in[3];
  const float* bf_ = (const float*)d_in[4];
  const float* Wix = (const float*)d_in[5];
  const float* Wih = (const float*)d_in[6];
  const float* bi_ = (const float*)d_in[7];
  const float* Wox = (const float*)d_in[8];
  const float* Woh = (const float*)d_in[9];
  const float* bo_ = (const float*)d_in[10];
  const float* Wcx = (const float*)d_in[11];
  const float* bc_ = (const float*)d_in[12];
  const float* Wph = (const float*)d_in[13];
  const float* bp_ = (const float*)d_in[14];

  char* ws = (char*)d_ws;
  float*          G    = (float*)(ws);                      // 24 KB   @ 0
  unsigned short* hfin = (unsigned short*)(ws + 32768);     // 256 KB  @ 32K
  char*           cbuf = (char*)(ws + 524288);              // 512 KB  @ 512K (2 par x 16 bt x 16KB)
  unsigned*       flg  = (unsigned*)(ws + 1048576);         // 2 KB    @ 1M
  unsigned short* pk2  = (unsigned short*)(ws + 1114112);   // 1 MB    @ 1M+64K
  unsigned short* pko  = (unsigned short*)(ws + 2162688);   // 512 KB  @ 2M+64K

  hipMemsetAsync(flg, 0, 2048, stream);                     // fresh flags every call
  hipLaunchKernelGGL(k_gates,   dim3(24),  dim3(256), 0, stream,
                     emb, Wfx, bf_, Wix, bi_, Wcx, bc_, Wox, bo_, G);
  hipLaunchKernelGGL(k_pack_fi, dim3(256), dim3(256), 0, stream, Wfh, Wih, pk2);
  hipLaunchKernelGGL(k_pack_o,  dim3(128), dim3(256), 0, stream, Woh, pko);
  hipLaunchKernelGGL(k_scan,    dim3(32),  dim3(256), P * 16384 + 3264, stream,
                     x, G, pk2, pko, cbuf, flg, hfin);
  hipLaunchKernelGGL(k_head,    dim3(256), dim3(64),  0, stream, hfin, Wph, bp_, (float*)d_out);
}

// Round 9
// 2012.153 us; speedup vs baseline: 4.2548x; 2.7449x over previous
//
#include <hip/hip_runtime.h>
#include <stdint.h>

#define TLEN 512
#define HDIM 512
#define DDIM 128
#define NCLS 10

typedef float f32x4 __attribute__((ext_vector_type(4)));
typedef short bf16x8 __attribute__((ext_vector_type(8)));
typedef unsigned long long u64;

__device__ __forceinline__ unsigned short f2bf(float f) {
  union { float f; unsigned u; } v; v.f = f;
  return (unsigned short)((v.u + 0x7FFFu + ((v.u >> 16) & 1u)) >> 16);
}
__device__ __forceinline__ float bf2f(unsigned short h) {
  union { unsigned u; float f; } v; v.u = ((unsigned)h) << 16; return v.f;
}
__device__ __forceinline__ float sigm(float x) {
  return __builtin_amdgcn_rcpf(1.0f + __expf(-x));
}
__device__ __forceinline__ void astw(unsigned* p, unsigned v) {
  __hip_atomic_store(p, v, __ATOMIC_RELAXED, __HIP_MEMORY_SCOPE_AGENT);
}

// agent-scope (MALL) batched 16B load — same cache bits LLVM emits for
// __hip_atomic_load(AGENT); issued untracked so they batch, ONE vmcnt wait.
#define GLOAD_SC1(dst, addr) \
  asm volatile("global_load_dwordx4 %0, %1, off sc1" : "=&v"(dst) : "v"(addr))
#define VMWAIT() do { asm volatile("s_waitcnt vmcnt(0)" ::: "memory"); \
                      __builtin_amdgcn_sched_barrier(0); } while (0)

// ---------------- gate tables: G[g][v][h], g in {f,i,c(pre-sigmoided),o} ----
__global__ void k_gates(const float* __restrict__ emb,
                        const float* __restrict__ Wfx, const float* __restrict__ bf_,
                        const float* __restrict__ Wix, const float* __restrict__ bi_,
                        const float* __restrict__ Wcx, const float* __restrict__ bc_,
                        const float* __restrict__ Wox, const float* __restrict__ bo_,
                        float* __restrict__ G) {
  int tid = blockIdx.x * 256 + threadIdx.x;          // 0..6143
  int h = tid & (HDIM - 1);
  int v = (tid >> 9) % 3;
  int g = tid / (3 * HDIM);
  const float* W; const float* bb;
  if (g == 0)      { W = Wfx; bb = bf_; }
  else if (g == 1) { W = Wix; bb = bi_; }
  else if (g == 2) { W = Wcx; bb = bc_; }
  else             { W = Wox; bb = bo_; }
  const float* e = emb + v * DDIM;
  const float* w = W + h * DDIM;
  float s = bb[h];
  #pragma unroll 8
  for (int d = 0; d < DDIM; ++d) s += e[d] * w[d];
  if (g == 2) s = sigm(s);                           // pre-sigmoid the c-gate
  G[tid] = s;
}

// ---------------- weight pack: register-resident B-fragments ----------------
// pk2: [hs(8)][nt(4)][gate(2)][kt(16)][lane(64)][e(8)] bf16
__global__ void k_pack_fi(const float* __restrict__ Wfh, const float* __restrict__ Wih,
                          unsigned short* __restrict__ pk) {
  int tid = blockIdx.x * 256 + threadIdx.x;          // 0..65535
  int l  = tid & 63;
  int kt = (tid >> 6) & 15;
  int g  = (tid >> 10) & 1;
  int nt = (tid >> 11) & 3;
  int hs = (tid >> 13) & 7;
  int n  = hs * 64 + nt * 16 + (l & 15);
  int k0 = kt * 32 + (l >> 4) * 8;
  const float* src = (g ? Wih : Wfh) + n * HDIM + k0;
  unsigned short* dst = pk + (size_t)tid * 8;
  #pragma unroll
  for (int e = 0; e < 8; ++e) dst[e] = f2bf(src[e]);
}

// pko: [hs(8)][nt(4)][kt(16)][lane(64)][e(8)] bf16
__global__ void k_pack_o(const float* __restrict__ Woh, unsigned short* __restrict__ pk) {
  int tid = blockIdx.x * 256 + threadIdx.x;          // 0..32767
  int l  = tid & 63;
  int kt = (tid >> 6) & 15;
  int nt = (tid >> 10) & 3;
  int hs = (tid >> 12) & 7;
  int n  = hs * 64 + nt * 16 + (l & 15);
  int k0 = kt * 32 + (l >> 4) * 8;
  const float* src = Woh + n * HDIM + k0;
  unsigned short* dst = pk + (size_t)tid * 8;
  #pragma unroll
  for (int e = 0; e < 8; ++e) dst[e] = f2bf(src[e]);
}

// ---------------- scan: 128 WGs = 16 batch-tiles x 8 h-slices ---------------
// Per WG: M=16 rows, N=64 cols, K=512; weights in regs all 512 steps.
// Exchange: SELF-VALIDATING tagged words (t+1)<<16 | bf16(c), agent scope.
// One MALL round trip per poll sample; no flag, no drain; 1 barrier/step.
// cbuf32 layout: [par(2)][bt(16)][kt(16)][row(16)][word(32)] u32.
__global__ __launch_bounds__(256, 1)
void k_scan(const int* __restrict__ x, const float* __restrict__ G,
            const unsigned short* __restrict__ pk2,
            const unsigned short* __restrict__ pko,
            char* __restrict__ cbuf,
            unsigned short* __restrict__ hfin) {
  __shared__ float gts[12][68];
  __shared__ unsigned char xv[16][516];
  __shared__ uint4 lds_a[16][64];                    // packed A-frag share (16 KB)

  const int tid  = threadIdx.x;
  const int lane = tid & 63;
  const int w    = tid >> 6;                         // wave = nt (0..3)
  const int bt   = blockIdx.x & 15;
  const int hs   = blockIdx.x >> 4;

  for (int jj = tid; jj < 12 * 64; jj += 256) {
    int gv = jj >> 6, c = jj & 63;
    gts[gv][c] = G[gv * HDIM + hs * 64 + c];
  }
  for (int jj = tid; jj < 16 * TLEN; jj += 256) {
    int r = jj >> 9, tt = jj & (TLEN - 1);
    xv[r][tt] = (unsigned char)x[(bt * 16 + r) * TLEN + tt];
  }

  bf16x8 wf[16], wi[16];
  {
    const bf16x8* ws = (const bf16x8*)pk2 + (size_t)((hs * 4 + w) * 2) * (16 * 64) + lane;
    #pragma unroll
    for (int kt = 0; kt < 16; ++kt) { wf[kt] = ws[kt * 64]; wi[kt] = ws[(16 + kt) * 64]; }
  }

  bf16x8 afr[16];
  #pragma unroll
  for (int kt = 0; kt < 16; ++kt) afr[kt] = bf16x8{0,0,0,0,0,0,0,0};  // c_0 = 0

  float cf[4] = {0.f, 0.f, 0.f, 0.f};
  const int rgrp = (lane >> 4) * 4;                  // C/D row base (batch row)
  const int coll = lane & 15;                        // C/D col (within 16-tile)
  const int col  = w * 16 + coll;                    // h col within slice [0,64)
  const int ktp  = 2 * hs + (col >> 5);              // producer's kt
  const int wrdo = col & 31;                         // producer's word in row
  // producer byte base within (par,bt): kt*2048 + row*128 + word*4
  const int pofs = ktp * 2048 + rgrp * 128 + wrdo * 4;
  // consumer byte base within (par,bt): row(l&15)*128 + kchunk(l>>4)*32
  const int cofs = (lane & 15) * 128 + (lane >> 4) * 32;
  const f32x4 zz = {0.f, 0.f, 0.f, 0.f};

  __syncthreads();

  for (int t = 0; t < TLEN - 1; ++t) {
    f32x4 af = zz, ai = zz;
    #pragma unroll
    for (int kt = 0; kt < 16; ++kt) {
      af = __builtin_amdgcn_mfma_f32_16x16x32_bf16(afr[kt], wf[kt], af, 0, 0, 0);
      ai = __builtin_amdgcn_mfma_f32_16x16x32_bf16(afr[kt], wi[kt], ai, 0, 0, 0);
    }
    const unsigned tg  = (unsigned)(t + 1);
    const unsigned tgh = tg << 16;
    char* tbase = cbuf + (size_t)((tg & 1) * 16 + bt) * 32768;

    #pragma unroll
    for (int r = 0; r < 4; ++r) {
      int vv = xv[rgrp + r][t];
      float fg = sigm(af[r] + gts[0 + vv][col]);
      float ig = sigm(ai[r] + gts[3 + vv][col]);
      float sc = gts[6 + vv][col];                   // pre-sigmoided c-gate
      float cn = sc * ig + cf[r] * fg;
      cf[r] = cn;
      astw((unsigned*)(tbase + pofs + r * 128), tgh | (unsigned)f2bf(cn));
    }

    // ---- poll own quarter (tags self-validate; 1 RT per sample) -----------
    const char* qb = tbase + cofs;
    uint4 d0, d1, d2, d3, d4, d5, d6, d7;
    unsigned bad;
    do {
      GLOAD_SC1(d0, qb + ((w << 2) | 0) * 2048);
      GLOAD_SC1(d1, qb + ((w << 2) | 0) * 2048 + 16);
      GLOAD_SC1(d2, qb + ((w << 2) | 1) * 2048);
      GLOAD_SC1(d3, qb + ((w << 2) | 1) * 2048 + 16);
      GLOAD_SC1(d4, qb + ((w << 2) | 2) * 2048);
      GLOAD_SC1(d5, qb + ((w << 2) | 2) * 2048 + 16);
      GLOAD_SC1(d6, qb + ((w << 2) | 3) * 2048);
      GLOAD_SC1(d7, qb + ((w << 2) | 3) * 2048 + 16);
      VMWAIT();
      unsigned m = 0;
      m |= (d0.x ^ tgh) | (d0.y ^ tgh) | (d0.z ^ tgh) | (d0.w ^ tgh);
      m |= (d1.x ^ tgh) | (d1.y ^ tgh) | (d1.z ^ tgh) | (d1.w ^ tgh);
      m |= (d2.x ^ tgh) | (d2.y ^ tgh) | (d2.z ^ tgh) | (d2.w ^ tgh);
      m |= (d3.x ^ tgh) | (d3.y ^ tgh) | (d3.z ^ tgh) | (d3.w ^ tgh);
      m |= (d4.x ^ tgh) | (d4.y ^ tgh) | (d4.z ^ tgh) | (d4.w ^ tgh);
      m |= (d5.x ^ tgh) | (d5.y ^ tgh) | (d5.z ^ tgh) | (d5.w ^ tgh);
      m |= (d6.x ^ tgh) | (d6.y ^ tgh) | (d6.z ^ tgh) | (d6.w ^ tgh);
      m |= (d7.x ^ tgh) | (d7.y ^ tgh) | (d7.z ^ tgh) | (d7.w ^ tgh);
      bad = m & 0xFFFF0000u;
    } while (__any(bad != 0));

    // ---- pack (strip tags) and share via LDS -------------------------------
    {
      uint4 q;
      q.x = __builtin_amdgcn_perm(d0.y, d0.x, 0x05040100);
      q.y = __builtin_amdgcn_perm(d0.w, d0.z, 0x05040100);
      q.z = __builtin_amdgcn_perm(d1.y, d1.x, 0x05040100);
      q.w = __builtin_amdgcn_perm(d1.w, d1.z, 0x05040100);
      lds_a[(w << 2) | 0][lane] = q;
      q.x = __builtin_amdgcn_perm(d2.y, d2.x, 0x05040100);
      q.y = __builtin_amdgcn_perm(d2.w, d2.z, 0x05040100);
      q.z = __builtin_amdgcn_perm(d3.y, d3.x, 0x05040100);
      q.w = __builtin_amdgcn_perm(d3.w, d3.z, 0x05040100);
      lds_a[(w << 2) | 1][lane] = q;
      q.x = __builtin_amdgcn_perm(d4.y, d4.x, 0x05040100);
      q.y = __builtin_amdgcn_perm(d4.w, d4.z, 0x05040100);
      q.z = __builtin_amdgcn_perm(d5.y, d5.x, 0x05040100);
      q.w = __builtin_amdgcn_perm(d5.w, d5.z, 0x05040100);
      lds_a[(w << 2) | 2][lane] = q;
      q.x = __builtin_amdgcn_perm(d6.y, d6.x, 0x05040100);
      q.y = __builtin_amdgcn_perm(d6.w, d6.z, 0x05040100);
      q.z = __builtin_amdgcn_perm(d7.y, d7.x, 0x05040100);
      q.w = __builtin_amdgcn_perm(d7.w, d7.z, 0x05040100);
      lds_a[(w << 2) | 3][lane] = q;
    }
    __syncthreads();                                 // quarters visible to all waves
    #pragma unroll
    for (int kt = 0; kt < 16; ++kt) {
      union { uint4 q; bf16x8 v; } u;
      u.q = lds_a[kt][lane];
      afr[kt] = u.v;
    }
  }

  // ---- final step t = 511: f, i and o gates; h = tanh(c)*o -----------------
  {
    const int t = TLEN - 1;
    f32x4 af = zz, ai = zz, ao = zz;
    #pragma unroll
    for (int kt = 0; kt < 16; ++kt) {
      af = __builtin_amdgcn_mfma_f32_16x16x32_bf16(afr[kt], wf[kt], af, 0, 0, 0);
      ai = __builtin_amdgcn_mfma_f32_16x16x32_bf16(afr[kt], wi[kt], ai, 0, 0, 0);
    }
    bf16x8 wo[16];
    const bf16x8* os = (const bf16x8*)pko + (size_t)(hs * 4 + w) * (16 * 64) + lane;
    #pragma unroll
    for (int kt = 0; kt < 16; ++kt) wo[kt] = os[kt * 64];
    #pragma unroll
    for (int kt = 0; kt < 16; ++kt)
      ao = __builtin_amdgcn_mfma_f32_16x16x32_bf16(afr[kt], wo[kt], ao, 0, 0, 0);
    #pragma unroll
    for (int r = 0; r < 4; ++r) {
      int vv = xv[rgrp + r][t];
      float fg = sigm(af[r] + gts[0 + vv][col]);
      float ig = sigm(ai[r] + gts[3 + vv][col]);
      float sc = gts[6 + vv][col];
      float cn = sc * ig + cf[r] * fg;
      float og = sigm(ao[r] + gts[9 + vv][col]);
      float hv = tanhf(cn) * og;
      hfin[(bt * 16 + rgrp + r) * HDIM + hs * 64 + col] = f2bf(hv);
    }
  }
}

// ---------------- classifier head + log_softmax: one wave per row -----------
__global__ __launch_bounds__(64)
void k_head(const unsigned short* __restrict__ hfin, const float* __restrict__ Wph,
            const float* __restrict__ bp, float* __restrict__ out) {
  const int b = blockIdx.x;
  const int lane = threadIdx.x;
  float acc[NCLS];
  #pragma unroll
  for (int c = 0; c < NCLS; ++c) acc[c] = 0.f;
  const unsigned short* hrow = hfin + (size_t)b * HDIM;
  for (int k = lane; k < HDIM; k += 64) {
    float hv = bf2f(hrow[k]);
    #pragma unroll
    for (int c = 0; c < NCLS; ++c) acc[c] += hv * Wph[c * HDIM + k];
  }
  #pragma unroll
  for (int c = 0; c < NCLS; ++c)
    #pragma unroll
    for (int off = 32; off > 0; off >>= 1)
      acc[c] += __shfl_down(acc[c], off, 64);
  if (lane == 0) {
    float p[NCLS]; float m = -1e30f;
    #pragma unroll
    for (int c = 0; c < NCLS; ++c) { p[c] = acc[c] + bp[c]; m = fmaxf(m, p[c]); }
    float s = 0.f;
    #pragma unroll
    for (int c = 0; c < NCLS; ++c) s += __expf(p[c] - m);
    const float ls = __logf(s);
    #pragma unroll
    for (int c = 0; c < NCLS; ++c) out[b * NCLS + c] = p[c] - m - ls;
  }
}

extern "C" void kernel_launch(void* const* d_in, const int* in_sizes, int n_in,
                              void* d_out, int out_size, void* d_ws, size_t ws_size,
                              hipStream_t stream) {
  const int*   x   = (const int*)d_in[0];
  const float* emb = (const float*)d_in[1];
  const float* Wfx = (const float*)d_in[2];
  const float* Wfh = (const float*)d_in[3];
  const float* bf_ = (const float*)d_in[4];
  const float* Wix = (const float*)d_in[5];
  const float* Wih = (const float*)d_in[6];
  const float* bi_ = (const float*)d_in[7];
  const float* Wox = (const float*)d_in[8];
  const float* Woh = (const float*)d_in[9];
  const float* bo_ = (const float*)d_in[10];
  const float* Wcx = (const float*)d_in[11];
  const float* bc_ = (const float*)d_in[12];
  const float* Wph = (const float*)d_in[13];
  const float* bp_ = (const float*)d_in[14];

  char* ws = (char*)d_ws;
  float*          G    = (float*)(ws);                      // 24 KB   @ 0
  unsigned short* hfin = (unsigned short*)(ws + 32768);     // 256 KB  @ 32K
  char*           cbuf = (char*)(ws + 524288);              // 1 MB    @ 512K (tagged, 2 par)
  unsigned short* pk2  = (unsigned short*)(ws + 1572864);   // 1 MB    @ 1.5M
  unsigned short* pko  = (unsigned short*)(ws + 2621440);   // 512 KB  @ 2.5M

  hipLaunchKernelGGL(k_gates,   dim3(24),  dim3(256), 0, stream,
                     emb, Wfx, bf_, Wix, bi_, Wcx, bc_, Wox, bo_, G);
  hipLaunchKernelGGL(k_pack_fi, dim3(256), dim3(256), 0, stream, Wfh, Wih, pk2);
  hipLaunchKernelGGL(k_pack_o,  dim3(128), dim3(256), 0, stream, Woh, pko);
  hipLaunchKernelGGL(k_scan,    dim3(128), dim3(256), 0, stream,
                     x, G, pk2, pko, cbuf, hfin);
  hipLaunchKernelGGL(k_head,    dim3(256), dim3(64),  0, stream, hfin, Wph, bp_, (float*)d_out);
}